// Round 2
// baseline (849.014 us; speedup 1.0000x reference)
//
#include <hip/hip_runtime.h>
#include <hip/hip_bf16.h>
#include <math.h>

#define N_NODES 100000
#define N_EDGES 1250000
#define D_IN    64
#define D_HID   64
#define N_CLS   40

#define NBUCK      1000      // buckets of BUCK_NODES nodes
#define BUCK_NODES 100
#define BUCK_CAP   1536      // mean 1250, sigma ~35 -> +8 sigma headroom
#define NBLK_STAGE 512
#define NBLK_GEMM1 1024
#define AGG1_PAD   65        // fp32 per row in LDS (pad 64 -> 65 kills bank alias)
#define AGG2_PAD   41        // fp32 per row in LDS (pad 40 -> 41)

typedef unsigned int uint;
typedef __attribute__((ext_vector_type(8))) short bf16x8;
typedef __attribute__((ext_vector_type(4))) float f32x4;

static __device__ __forceinline__ uint pack_bf16x2(float a, float b) {
    unsigned short ua = __builtin_bit_cast(unsigned short, __float2bfloat16(a));
    unsigned short ub = __builtin_bit_cast(unsigned short, __float2bfloat16(b));
    return (uint)ua | ((uint)ub << 16);
}
static __device__ __forceinline__ short f2bf(float f) {
    return (short)__builtin_bit_cast(unsigned short, __float2bfloat16(f));
}

// ---------------------------------------------------------------------------
// Fused K1: blocks [0, NBLK_STAGE) bucket the edge list (two in-block passes;
// LDS histogram -> one global atomic per nonempty bucket -> DENSE staged
// writes, which is what keeps WRITE_SIZE low). Remaining NBLK_GEMM1 blocks
// run MFMA GEMM 1: [y1 | r1] = bf16( x @ [W1_l | W1_r] (+ b1 on r) ).
// ---------------------------------------------------------------------------
__global__ __launch_bounds__(256, 3) void stage_and_gemm1(
    const int* __restrict__ src, const int* __restrict__ dst,
    int* __restrict__ bucketCnt, uint* __restrict__ staged,
    const float* __restrict__ x,
    const float* __restrict__ W_l, const float* __restrict__ W_r,
    const float* __restrict__ b,
    __hip_bfloat16* __restrict__ y1, __hip_bfloat16* __restrict__ r1,
    int ntiles)
{
    __shared__ int cntB[NBUCK], offB[NBUCK], gbase[NBUCK];

    if (blockIdx.x < NBLK_STAGE) {
        // ---- bucket_stage ----
        const int per = (N_EDGES + NBLK_STAGE - 1) / NBLK_STAGE;   // 2442
        const int e0 = blockIdx.x * per;
        const int e1 = (e0 + per < N_EDGES) ? e0 + per : N_EDGES;
        for (int i = threadIdx.x; i < NBUCK; i += 256) { cntB[i] = 0; offB[i] = 0; }
        __syncthreads();
        for (int e = e0 + threadIdx.x; e < e1; e += 256)
            atomicAdd(&cntB[dst[e] / BUCK_NODES], 1);
        __syncthreads();
        for (int i = threadIdx.x; i < NBUCK; i += 256) {
            int c = cntB[i];
            gbase[i] = c ? atomicAdd(&bucketCnt[i], c) : 0;
        }
        __syncthreads();
        for (int e = e0 + threadIdx.x; e < e1; e += 256) {
            int d = dst[e];
            int s = src[e];
            int bk = d / BUCK_NODES;
            int pos = gbase[bk] + atomicAdd(&offB[bk], 1);
            if (pos < BUCK_CAP)
                staged[(size_t)bk * BUCK_CAP + pos] =
                    (uint)s | ((uint)(d - bk * BUCK_NODES) << 17);
        }
        return;
    }

    // ---- gemm1 ----
    const int gbid = blockIdx.x - NBLK_STAGE;

    const int lane = threadIdx.x & 63;
    const int m = lane & 15;
    const int q = lane >> 4;

    bf16x8 bfrag[8][2];
    float  biasv[4];
    #pragma unroll
    for (int t = 0; t < 8; ++t) {
        const float* Wsrc = (t < 4) ? W_l : W_r;
        const int c = t * 16 + m - ((t < 4) ? 0 : 64);
        #pragma unroll
        for (int ks = 0; ks < 2; ++ks) {
            bf16x8 f;
            #pragma unroll
            for (int j = 0; j < 8; ++j)
                f[j] = f2bf(Wsrc[(ks * 32 + q * 8 + j) * 64 + c]);
            bfrag[t][ks] = f;
        }
    }
    #pragma unroll
    for (int t = 0; t < 4; ++t) biasv[t] = b[t * 16 + m];

    int wid = gbid * 4 + (threadIdx.x >> 6);
    const int nw = NBLK_GEMM1 * 4;
    for (int tile = wid; tile < ntiles; tile += nw) {
        const int node0 = tile * 16;
        const float* xrow = x + (size_t)(node0 + m) * 64 + q * 8;
        bf16x8 afrag[2];
        #pragma unroll
        for (int ks = 0; ks < 2; ++ks) {
            float4 f0 = *(const float4*)(xrow + ks * 32);
            float4 f1 = *(const float4*)(xrow + ks * 32 + 4);
            bf16x8 a;
            a[0] = f2bf(f0.x); a[1] = f2bf(f0.y); a[2] = f2bf(f0.z); a[3] = f2bf(f0.w);
            a[4] = f2bf(f1.x); a[5] = f2bf(f1.y); a[6] = f2bf(f1.z); a[7] = f2bf(f1.w);
            afrag[ks] = a;
        }
        f32x4 acc[8];
        #pragma unroll
        for (int t = 0; t < 8; ++t) acc[t] = (f32x4){0.f, 0.f, 0.f, 0.f};
        #pragma unroll
        for (int ks = 0; ks < 2; ++ks) {
            #pragma unroll
            for (int t = 0; t < 8; ++t)
                acc[t] = __builtin_amdgcn_mfma_f32_16x16x32_bf16(
                    afrag[ks], bfrag[t][ks], acc[t], 0, 0, 0);
        }
        #pragma unroll
        for (int t = 0; t < 8; ++t) {
            #pragma unroll
            for (int r = 0; r < 4; ++r) {
                const size_t row = (size_t)(node0 + q * 4 + r);
                if (t < 4)
                    y1[row * 64 + t * 16 + m] = __float2bfloat16(acc[t][r]);
                else
                    r1[row * 64 + (t - 4) * 16 + m] =
                        __float2bfloat16(acc[t][r] + biasv[t - 4]);
            }
        }
    }
}

// ---------------------------------------------------------------------------
// K2: bucket-local aggregation layer 1, fused with mean + residual + relu.
// One block OWNS one bucket of 100 nodes: fp32 accumulators in LDS
// (ds_add_f32), so NO slots array, NO ell_fill pass, NO bpermute.
// Per edge: 16 lanes read one 128 B y1 row coalesced, 4 LDS adds each.
// 8 edges-per-slot unrolled => 8 row-loads in flight per lane.
// ---------------------------------------------------------------------------
__global__ __launch_bounds__(256) void agg1_relu(
    const __hip_bfloat16* __restrict__ y1,   // [N][64]
    const uint* __restrict__ staged, const int* __restrict__ bucketCnt,
    __hip_bfloat16* __restrict__ h,          // in: r1 rows; out: h (in place)
    int* __restrict__ cnt)                   // out: degree per node
{
    __shared__ float agg[BUCK_NODES * AGG1_PAD];   // 26 KB
    __shared__ int   ldeg[BUCK_NODES];
    const int b = blockIdx.x;
    const int node0 = b * BUCK_NODES;
    for (int i = threadIdx.x; i < BUCK_NODES * AGG1_PAD; i += 256) agg[i] = 0.f;
    for (int i = threadIdx.x; i < BUCK_NODES; i += 256) ldeg[i] = 0;
    __syncthreads();

    int total = bucketCnt[b]; if (total > BUCK_CAP) total = BUCK_CAP;
    const uint* sp = staged + (size_t)b * BUCK_CAP;
    const char* y1c = (const char*)y1;
    const int lane16 = threadIdx.x & 15;
    const int eslot  = threadIdx.x >> 4;          // 16 edges in flight / block / k
    const uint dgoff = (uint)lane16 * 8u;

    for (int base = 0; base < total; base += 128) {
        uint v[8]; bool ok[8]; uint2 dv[8];
        #pragma unroll
        for (int k = 0; k < 8; ++k) {
            const int e = base + k * 16 + eslot;
            ok[k] = (e < total);
            v[k] = ok[k] ? sp[e] : 0u;
        }
        #pragma unroll
        for (int k = 0; k < 8; ++k) {
            const uint s = v[k] & 0x1FFFFu;
            dv[k] = ok[k] ? *(const uint2*)(y1c + (size_t)s * 128u + dgoff)
                          : make_uint2(0u, 0u);
        }
        #pragma unroll
        for (int k = 0; k < 8; ++k) {
            if (ok[k]) {
                const int ld = (int)(v[k] >> 17);
                float* ap = &agg[ld * AGG1_PAD + lane16 * 4];
                atomicAdd(ap + 0, __uint_as_float(dv[k].x << 16));
                atomicAdd(ap + 1, __uint_as_float(dv[k].x & 0xffff0000u));
                atomicAdd(ap + 2, __uint_as_float(dv[k].y << 16));
                atomicAdd(ap + 3, __uint_as_float(dv[k].y & 0xffff0000u));
                if (lane16 == 0) atomicAdd(&ldeg[ld], 1);
            }
        }
    }
    __syncthreads();

    // epilogue: h = relu(agg/deg + r1), dense writes; also publish degree
    for (int i = threadIdx.x; i < BUCK_NODES * 16; i += 256) {
        const int row = i >> 4, dg = i & 15;
        const int node = node0 + row;
        const int deg = ldeg[row];
        const float inv = 1.0f / (float)(deg > 1 ? deg : 1);
        char* hp = (char*)h + (size_t)node * 128u + (uint)dg * 8u;
        uint2 rr = *(const uint2*)hp;
        const float* ap = &agg[row * AGG1_PAD + dg * 4];
        float v0 = ap[0] * inv + __uint_as_float(rr.x << 16);
        float v1 = ap[1] * inv + __uint_as_float(rr.x & 0xffff0000u);
        float v2 = ap[2] * inv + __uint_as_float(rr.y << 16);
        float v3 = ap[3] * inv + __uint_as_float(rr.y & 0xffff0000u);
        v0 = v0 > 0.f ? v0 : 0.f; v1 = v1 > 0.f ? v1 : 0.f;
        v2 = v2 > 0.f ? v2 : 0.f; v3 = v3 > 0.f ? v3 : 0.f;
        uint2 o; o.x = pack_bf16x2(v0, v1); o.y = pack_bf16x2(v2, v3);
        *(uint2*)hp = o;
        if (dg == 0) cnt[node] = deg;
    }
}

// ---------------------------------------------------------------------------
// MFMA GEMM 2: [y2 | r2] = bf16( h @ [W2_l | W2_r] (+ b2 on r) ). 64 -> 80.
// ---------------------------------------------------------------------------
__global__ __launch_bounds__(256, 3) void gemm2_mfma(
    const __hip_bfloat16* __restrict__ h,
    const float* __restrict__ W_l, const float* __restrict__ W_r,
    const float* __restrict__ b,
    __hip_bfloat16* __restrict__ y2, __hip_bfloat16* __restrict__ r2,
    int ntiles)
{
    const int lane = threadIdx.x & 63;
    const int m = lane & 15;
    const int q = lane >> 4;

    bf16x8 bfrag[5][2];
    float  biasv[5];
    #pragma unroll
    for (int t = 0; t < 5; ++t) {
        const int g = t * 16 + m;
        const float* Wsrc = (g < N_CLS) ? W_l : W_r;
        const int c = (g < N_CLS) ? g : g - N_CLS;
        #pragma unroll
        for (int ks = 0; ks < 2; ++ks) {
            bf16x8 f;
            #pragma unroll
            for (int j = 0; j < 8; ++j)
                f[j] = f2bf(Wsrc[(ks * 32 + q * 8 + j) * N_CLS + c]);
            bfrag[t][ks] = f;
        }
        biasv[t] = (g >= N_CLS) ? b[g - N_CLS] : 0.0f;
    }

    int wid = blockIdx.x * 4 + (threadIdx.x >> 6);
    const int nw = gridDim.x * 4;
    for (int tile = wid; tile < ntiles; tile += nw) {
        const int node0 = tile * 16;
        const __hip_bfloat16* hrow = h + (size_t)(node0 + m) * 64 + q * 8;
        bf16x8 afrag[2];
        afrag[0] = *(const bf16x8*)(hrow);
        afrag[1] = *(const bf16x8*)(hrow + 32);
        f32x4 acc[5];
        #pragma unroll
        for (int t = 0; t < 5; ++t) acc[t] = (f32x4){0.f, 0.f, 0.f, 0.f};
        #pragma unroll
        for (int ks = 0; ks < 2; ++ks) {
            #pragma unroll
            for (int t = 0; t < 5; ++t)
                acc[t] = __builtin_amdgcn_mfma_f32_16x16x32_bf16(
                    afrag[ks], bfrag[t][ks], acc[t], 0, 0, 0);
        }
        #pragma unroll
        for (int t = 0; t < 5; ++t) {
            const int g = t * 16 + m;
            #pragma unroll
            for (int r = 0; r < 4; ++r) {
                const size_t row = (size_t)(node0 + q * 4 + r);
                float v = acc[t][r] + biasv[t];
                if (g < N_CLS) y2[row * N_CLS + g] = __float2bfloat16(v);
                else           r2[row * N_CLS + (g - N_CLS)] = __float2bfloat16(v);
            }
        }
    }
}

// ---------------------------------------------------------------------------
// K4: bucket-local aggregation layer 2, fused with mean + residual +
// log_softmax. Same LDS-accumulator scheme; y2 rows are 80 B so lanes
// 0..9 of each 16-lane group carry the row (4 LDS adds each).
// ---------------------------------------------------------------------------
__global__ __launch_bounds__(256) void agg2_lsm(
    const __hip_bfloat16* __restrict__ y2,   // [N][40]
    const __hip_bfloat16* __restrict__ r2,   // [N][40]
    const uint* __restrict__ staged, const int* __restrict__ bucketCnt,
    const int* __restrict__ cnt,
    float* __restrict__ out)
{
    __shared__ float agg[BUCK_NODES * AGG2_PAD];   // 16.4 KB
    const int b = blockIdx.x;
    const int node0 = b * BUCK_NODES;
    for (int i = threadIdx.x; i < BUCK_NODES * AGG2_PAD; i += 256) agg[i] = 0.f;
    __syncthreads();

    int total = bucketCnt[b]; if (total > BUCK_CAP) total = BUCK_CAP;
    const uint* sp = staged + (size_t)b * BUCK_CAP;
    const char* y2c = (const char*)y2;
    const int lane16 = threadIdx.x & 15;
    const int eslot  = threadIdx.x >> 4;
    const bool act = (lane16 < 10);               // 10 lanes x 8 B = 80 B row
    const uint dgoff = (uint)lane16 * 8u;

    for (int base = 0; base < total; base += 128) {
        uint v[8]; bool ok[8]; uint2 dv[8];
        #pragma unroll
        for (int k = 0; k < 8; ++k) {
            const int e = base + k * 16 + eslot;
            const bool in = (e < total);
            ok[k] = in && act;
            v[k] = in ? sp[e] : 0u;
        }
        #pragma unroll
        for (int k = 0; k < 8; ++k) {
            const uint s = v[k] & 0x1FFFFu;
            dv[k] = ok[k] ? *(const uint2*)(y2c + (size_t)s * 80u + dgoff)
                          : make_uint2(0u, 0u);
        }
        #pragma unroll
        for (int k = 0; k < 8; ++k) {
            if (ok[k]) {
                const int ld = (int)(v[k] >> 17);
                float* ap = &agg[ld * AGG2_PAD + lane16 * 4];
                atomicAdd(ap + 0, __uint_as_float(dv[k].x << 16));
                atomicAdd(ap + 1, __uint_as_float(dv[k].x & 0xffff0000u));
                atomicAdd(ap + 2, __uint_as_float(dv[k].y << 16));
                atomicAdd(ap + 3, __uint_as_float(dv[k].y & 0xffff0000u));
            }
        }
    }
    __syncthreads();

    // epilogue: log_softmax over 40 classes; one 32-lane half-wave per row
    const int half  = threadIdx.x >> 5;           // 0..7
    const int lpair = threadIdx.x & 31;
    const uint pre2 = (uint)(lpair < 20 ? lpair : 19) * 4u;
    for (int row = half; row < BUCK_NODES; row += 8) {
        const int node = node0 + row;
        const int deg = cnt[node];
        const float inv = 1.0f / (float)(deg > 1 ? deg : 1);
        uint rr = *(const uint*)((const char*)r2 + (size_t)node * 80u + pre2);
        float l0 = -INFINITY, l1 = -INFINITY;
        if (lpair < 20) {
            l0 = agg[row * AGG2_PAD + lpair * 2]     * inv + __uint_as_float(rr << 16);
            l1 = agg[row * AGG2_PAD + lpair * 2 + 1] * inv + __uint_as_float(rr & 0xffff0000u);
        }
        float m = fmaxf(l0, l1);
        #pragma unroll
        for (int off = 16; off > 0; off >>= 1)
            m = fmaxf(m, __shfl_xor(m, off));
        float ex = (lpair < 20) ? (expf(l0 - m) + expf(l1 - m)) : 0.0f;
        #pragma unroll
        for (int off = 16; off > 0; off >>= 1)
            ex += __shfl_xor(ex, off);
        float lg = m + logf(ex);
        if (lpair < 20) {
            float2 o = make_float2(l0 - lg, l1 - lg);
            *(float2*)(out + (size_t)node * N_CLS + lpair * 2) = o;
        }
    }
}

extern "C" void kernel_launch(void* const* d_in, const int* in_sizes, int n_in,
                              void* d_out, int out_size, void* d_ws, size_t ws_size,
                              hipStream_t stream)
{
    (void)in_sizes; (void)n_in; (void)out_size; (void)ws_size;

    const float* x    = (const float*)d_in[0];
    const int*   ei   = (const int*)d_in[1];      // [2, E]: src row, then dst row
    const float* W1_l = (const float*)d_in[2];
    const float* b1   = (const float*)d_in[3];
    const float* W1_r = (const float*)d_in[4];
    const float* W2_l = (const float*)d_in[5];
    const float* b2   = (const float*)d_in[6];
    const float* W2_r = (const float*)d_in[7];
    float* out = (float*)d_out;

    const int* src = ei;
    const int* dst = ei + N_EDGES;

    // workspace layout (bytes, ~44 MiB):
    //   bucketCnt : [0, 4000)
    //   cnt       : [4096, +400000)          int[N] degrees (written by agg1)
    //   staged    : [1M, +6.144MB)           u32[NBUCK*BUCK_CAP]
    //   y1/y2     : [8M, +12.8MB)            bf16[N*64]; y2 [N*40] overlays
    //   h (=r1)   : [21M, +12.8MB)           bf16[N*64]
    //   r2        : [34M, +8MB)              bf16[N*40]
    char* ws = (char*)d_ws;
    int*            bucketCnt = (int*)(ws);
    int*            cnt       = (int*)(ws + 4096);
    uint*           staged    = (uint*)(ws + (1u << 20));
    __hip_bfloat16* y1        = (__hip_bfloat16*)(ws + 8388608u);
    __hip_bfloat16* y2        = (__hip_bfloat16*)(ws + 8388608u);
    __hip_bfloat16* h         = (__hip_bfloat16*)(ws + 22020096u);  // also r1
    __hip_bfloat16* r2        = (__hip_bfloat16*)(ws + 35651584u);

    const int ntiles = N_NODES / 16;   // 6250, exact

    // K0: zero bucket counters; K1: edge bucketing || gemm1 (independent)
    hipMemsetAsync(bucketCnt, 0, NBUCK * sizeof(int), stream);
    stage_and_gemm1<<<NBLK_STAGE + NBLK_GEMM1, 256, 0, stream>>>(
        src, dst, bucketCnt, staged, x, W1_l, W1_r, b1, y1, h, ntiles);

    // K2: bucket-local LDS aggregation + mean + residual + relu
    agg1_relu<<<NBUCK, 256, 0, stream>>>(y1, staged, bucketCnt, h, cnt);

    // K3: gemm2
    gemm2_mfma<<<1024, 256, 0, stream>>>(h, W2_l, W2_r, b2, y2, r2, ntiles);

    // K4: bucket-local LDS aggregation + mean + residual + log_softmax
    agg2_lsm<<<NBUCK, 256, 0, stream>>>(y2, r2, staged, bucketCnt, cnt, out);
}

// Round 3
// 193.985 us; speedup vs baseline: 4.3767x; 4.3767x over previous
//
#include <hip/hip_runtime.h>
#include <hip/hip_bf16.h>
#include <math.h>

#define N_NODES 100000
#define N_EDGES 1250000
#define D_IN    64
#define D_HID   64
#define N_CLS   40

#define NBUCK      500       // staging buckets of BUCK_NODES nodes
#define BUCK_NODES 200
#define BUCK_CAP   2944      // mean 2500, sigma ~50 -> +8.8 sigma headroom
#define NBLK_STAGE 512
#define NBLK_GEMM1 1024
#define ELL_W      44        // Poisson(12.5) tail @44 ~ 3e-12/node
#define GNODES     100       // nodes per gather block (half a staging bucket)

typedef unsigned int uint;
typedef __attribute__((ext_vector_type(8))) short bf16x8;
typedef __attribute__((ext_vector_type(4))) float f32x4;

static __device__ __forceinline__ uint pack_bf16x2(float a, float b) {
    unsigned short ua = __builtin_bit_cast(unsigned short, __float2bfloat16(a));
    unsigned short ub = __builtin_bit_cast(unsigned short, __float2bfloat16(b));
    return (uint)ua | ((uint)ub << 16);
}
static __device__ __forceinline__ short f2bf(float f) {
    return (short)__builtin_bit_cast(unsigned short, __float2bfloat16(f));
}

// ---------------------------------------------------------------------------
// Fused K1: blocks [0, NBLK_STAGE) bucket the edge list (two in-block passes;
// LDS histogram -> one global atomic per nonempty bucket -> DENSE staged
// writes: this density is what keeps WRITE_SIZE low, proven R0 vs R1).
// Remaining NBLK_GEMM1 blocks run MFMA GEMM 1:
//   [y1 | r1] = bf16( x @ [W1_l | W1_r] (+ b1 on r) ).
// Gemm-block 0 also zeroes y1's dummy row (gather pad target).
// ---------------------------------------------------------------------------
__global__ __launch_bounds__(256, 3) void stage_and_gemm1(
    const int* __restrict__ src, const int* __restrict__ dst,
    int* __restrict__ bucketCnt, uint* __restrict__ staged,
    const float* __restrict__ x,
    const float* __restrict__ W_l, const float* __restrict__ W_r,
    const float* __restrict__ b,
    __hip_bfloat16* __restrict__ y1, __hip_bfloat16* __restrict__ r1,
    int ntiles)
{
    __shared__ int cntB[NBUCK], offB[NBUCK], gbase[NBUCK];

    if (blockIdx.x < NBLK_STAGE) {
        // ---- bucket_stage ----
        const int per = (N_EDGES + NBLK_STAGE - 1) / NBLK_STAGE;   // 2442
        const int e0 = blockIdx.x * per;
        const int e1 = (e0 + per < N_EDGES) ? e0 + per : N_EDGES;
        for (int i = threadIdx.x; i < NBUCK; i += 256) { cntB[i] = 0; offB[i] = 0; }
        __syncthreads();
        for (int e = e0 + threadIdx.x; e < e1; e += 256)
            atomicAdd(&cntB[dst[e] / BUCK_NODES], 1);
        __syncthreads();
        for (int i = threadIdx.x; i < NBUCK; i += 256) {
            int c = cntB[i];
            gbase[i] = c ? atomicAdd(&bucketCnt[i], c) : 0;
        }
        __syncthreads();
        for (int e = e0 + threadIdx.x; e < e1; e += 256) {
            int d = dst[e];
            int s = src[e];
            int bk = d / BUCK_NODES;
            int pos = gbase[bk] + atomicAdd(&offB[bk], 1);
            if (pos < BUCK_CAP)
                staged[(size_t)bk * BUCK_CAP + pos] =
                    (uint)s | ((uint)(d - bk * BUCK_NODES) << 17);
        }
        return;
    }

    // ---- gemm1 ----
    const int gbid = blockIdx.x - NBLK_STAGE;
    if (gbid == 0 && threadIdx.x < 64)
        y1[(size_t)N_NODES * 64 + threadIdx.x] = __float2bfloat16(0.0f);

    const int lane = threadIdx.x & 63;
    const int m = lane & 15;
    const int q = lane >> 4;

    bf16x8 bfrag[8][2];
    float  biasv[4];
    #pragma unroll
    for (int t = 0; t < 8; ++t) {
        const float* Wsrc = (t < 4) ? W_l : W_r;
        const int c = t * 16 + m - ((t < 4) ? 0 : 64);
        #pragma unroll
        for (int ks = 0; ks < 2; ++ks) {
            bf16x8 f;
            #pragma unroll
            for (int j = 0; j < 8; ++j)
                f[j] = f2bf(Wsrc[(ks * 32 + q * 8 + j) * 64 + c]);
            bfrag[t][ks] = f;
        }
    }
    #pragma unroll
    for (int t = 0; t < 4; ++t) biasv[t] = b[t * 16 + m];

    int wid = gbid * 4 + (threadIdx.x >> 6);
    const int nw = NBLK_GEMM1 * 4;
    for (int tile = wid; tile < ntiles; tile += nw) {
        const int node0 = tile * 16;
        const float* xrow = x + (size_t)(node0 + m) * 64 + q * 8;
        bf16x8 afrag[2];
        #pragma unroll
        for (int ks = 0; ks < 2; ++ks) {
            float4 f0 = *(const float4*)(xrow + ks * 32);
            float4 f1 = *(const float4*)(xrow + ks * 32 + 4);
            bf16x8 a;
            a[0] = f2bf(f0.x); a[1] = f2bf(f0.y); a[2] = f2bf(f0.z); a[3] = f2bf(f0.w);
            a[4] = f2bf(f1.x); a[5] = f2bf(f1.y); a[6] = f2bf(f1.z); a[7] = f2bf(f1.w);
            afrag[ks] = a;
        }
        f32x4 acc[8];
        #pragma unroll
        for (int t = 0; t < 8; ++t) acc[t] = (f32x4){0.f, 0.f, 0.f, 0.f};
        #pragma unroll
        for (int ks = 0; ks < 2; ++ks) {
            #pragma unroll
            for (int t = 0; t < 8; ++t)
                acc[t] = __builtin_amdgcn_mfma_f32_16x16x32_bf16(
                    afrag[ks], bfrag[t][ks], acc[t], 0, 0, 0);
        }
        #pragma unroll
        for (int t = 0; t < 8; ++t) {
            #pragma unroll
            for (int r = 0; r < 4; ++r) {
                const size_t row = (size_t)(node0 + q * 4 + r);
                if (t < 4)
                    y1[row * 64 + t * 16 + m] = __float2bfloat16(acc[t][r]);
                else
                    r1[row * 64 + (t - 4) * 16 + m] =
                        __float2bfloat16(acc[t][r] + biasv[t - 4]);
            }
        }
    }
}

// ---------------------------------------------------------------------------
// K2: per-block LDS-ELL build + gather + relu.  Block owns GNODES=100 nodes
// (half a staging bucket): scans the parent bucket, keeps its half, builds
// lslots/lcnt in LDS (1 int LDS atomic per edge), then runs the R0 gather
// body (bpermute + coalesced uint2 row loads + shuffle reduce) with indices
// from LDS.  No global slots/cnt arrays, no separate ell_fill dispatch.
// ---------------------------------------------------------------------------
__global__ __launch_bounds__(512) void bucket_gather1(
    const __hip_bfloat16* __restrict__ y1,   // [N+1][64], row N zeroed
    const uint* __restrict__ staged, const int* __restrict__ bucketCnt,
    __hip_bfloat16* __restrict__ h)          // in: r1 rows; out: h (in place)
{
    __shared__ int lcnt[GNODES];
    __shared__ int lslots[GNODES * ELL_W + 64];
    const int pb = blockIdx.x >> 1;          // parent staging bucket
    const int hf = blockIdx.x & 1;           // which half we own
    const int node0 = pb * BUCK_NODES + hf * GNODES;

    for (int i = threadIdx.x; i < GNODES; i += 512) lcnt[i] = 0;
    __syncthreads();

    int total = bucketCnt[pb]; if (total > BUCK_CAP) total = BUCK_CAP;
    const uint* sp = staged + (size_t)pb * BUCK_CAP;
    const int rel0 = hf * GNODES;
    for (int i = threadIdx.x; i < total; i += 512) {
        uint v = sp[i];
        int rel = (int)(v >> 17) - rel0;
        if (0 <= rel && rel < GNODES) {
            int pos = atomicAdd(&lcnt[rel], 1);
            if (pos < ELL_W) lslots[rel * ELL_W + pos] = (int)(v & 0x1FFFFu);
        }
    }
    __syncthreads();

    const int lane = threadIdx.x & 63;
    const int wv   = threadIdx.x >> 6;       // 0..7
    const int q4   = (lane >> 4) * 4;
    const int pre  = (lane & 15) * 8;
    const char* y1c = (const char*)y1;

    for (int n = wv; n < GNODES; n += 8) {
        const int node = node0 + n;
        const int degr = lcnt[n];
        const int idxv = lslots[n * ELL_W + lane];     // garbage beyond degc: guarded
        const int degc = degr < ELL_W ? degr : ELL_W;
        int idx = (lane >= degc) ? N_NODES : idxv;     // pad -> zero dummy row

        float a0 = 0.f, a1 = 0.f, a2 = 0.f, a3 = 0.f;
        const int groups = (degc + 15) & ~15;
        for (int e = 0; e < groups; e += 16) {
            int sel0 = __builtin_amdgcn_ds_bpermute(e * 4      + q4, idx);
            int sel1 = __builtin_amdgcn_ds_bpermute(e * 4 + 16 + q4, idx);
            int sel2 = __builtin_amdgcn_ds_bpermute(e * 4 + 32 + q4, idx);
            int sel3 = __builtin_amdgcn_ds_bpermute(e * 4 + 48 + q4, idx);
            uint2 d0 = *(const uint2*)(y1c + ((size_t)(uint)sel0 * 128u + (uint)pre));
            uint2 d1 = *(const uint2*)(y1c + ((size_t)(uint)sel1 * 128u + (uint)pre));
            uint2 d2 = *(const uint2*)(y1c + ((size_t)(uint)sel2 * 128u + (uint)pre));
            uint2 d3 = *(const uint2*)(y1c + ((size_t)(uint)sel3 * 128u + (uint)pre));
            a0 += __uint_as_float(d0.x << 16) + __uint_as_float(d1.x << 16)
                + __uint_as_float(d2.x << 16) + __uint_as_float(d3.x << 16);
            a1 += __uint_as_float(d0.x & 0xffff0000u) + __uint_as_float(d1.x & 0xffff0000u)
                + __uint_as_float(d2.x & 0xffff0000u) + __uint_as_float(d3.x & 0xffff0000u);
            a2 += __uint_as_float(d0.y << 16) + __uint_as_float(d1.y << 16)
                + __uint_as_float(d2.y << 16) + __uint_as_float(d3.y << 16);
            a3 += __uint_as_float(d0.y & 0xffff0000u) + __uint_as_float(d1.y & 0xffff0000u)
                + __uint_as_float(d2.y & 0xffff0000u) + __uint_as_float(d3.y & 0xffff0000u);
        }
        a0 += __shfl_xor(a0, 16); a0 += __shfl_xor(a0, 32);
        a1 += __shfl_xor(a1, 16); a1 += __shfl_xor(a1, 32);
        a2 += __shfl_xor(a2, 16); a2 += __shfl_xor(a2, 32);
        a3 += __shfl_xor(a3, 16); a3 += __shfl_xor(a3, 32);

        uint2 rr = *(const uint2*)((const char*)h + ((size_t)node * 128u + (uint)pre));
        float r0  = __uint_as_float(rr.x << 16);
        float r1v = __uint_as_float(rr.x & 0xffff0000u);
        float r2v = __uint_as_float(rr.y << 16);
        float r3  = __uint_as_float(rr.y & 0xffff0000u);

        float inv = 1.0f / (float)(degr > 1 ? degr : 1);
        float v0 = a0 * inv + r0;  v0 = v0 > 0.f ? v0 : 0.f;
        float v1 = a1 * inv + r1v; v1 = v1 > 0.f ? v1 : 0.f;
        float v2 = a2 * inv + r2v; v2 = v2 > 0.f ? v2 : 0.f;
        float v3 = a3 * inv + r3;  v3 = v3 > 0.f ? v3 : 0.f;

        if (lane < 16) {
            uint2 o;
            o.x = pack_bf16x2(v0, v1);
            o.y = pack_bf16x2(v2, v3);
            *(uint2*)((char*)h + ((size_t)node * 128u + (uint)pre)) = o;
        }
    }
}

// ---------------------------------------------------------------------------
// MFMA GEMM 2: [y2 | r2] = bf16( h @ [W2_l | W2_r] (+ b2 on r) ). 64 -> 80.
// Block 0 also zeroes y2's dummy row.
// ---------------------------------------------------------------------------
__global__ __launch_bounds__(256, 3) void gemm2_mfma(
    const __hip_bfloat16* __restrict__ h,
    const float* __restrict__ W_l, const float* __restrict__ W_r,
    const float* __restrict__ b,
    __hip_bfloat16* __restrict__ y2, __hip_bfloat16* __restrict__ r2,
    int ntiles)
{
    if (blockIdx.x == 0 && threadIdx.x < N_CLS)
        y2[(size_t)N_NODES * N_CLS + threadIdx.x] = __float2bfloat16(0.0f);

    const int lane = threadIdx.x & 63;
    const int m = lane & 15;
    const int q = lane >> 4;

    bf16x8 bfrag[5][2];
    float  biasv[5];
    #pragma unroll
    for (int t = 0; t < 5; ++t) {
        const int g = t * 16 + m;
        const float* Wsrc = (g < N_CLS) ? W_l : W_r;
        const int c = (g < N_CLS) ? g : g - N_CLS;
        #pragma unroll
        for (int ks = 0; ks < 2; ++ks) {
            bf16x8 f;
            #pragma unroll
            for (int j = 0; j < 8; ++j)
                f[j] = f2bf(Wsrc[(ks * 32 + q * 8 + j) * N_CLS + c]);
            bfrag[t][ks] = f;
        }
        biasv[t] = (g >= N_CLS) ? b[g - N_CLS] : 0.0f;
    }

    int wid = blockIdx.x * 4 + (threadIdx.x >> 6);
    const int nw = gridDim.x * 4;
    for (int tile = wid; tile < ntiles; tile += nw) {
        const int node0 = tile * 16;
        const __hip_bfloat16* hrow = h + (size_t)(node0 + m) * 64 + q * 8;
        bf16x8 afrag[2];
        afrag[0] = *(const bf16x8*)(hrow);
        afrag[1] = *(const bf16x8*)(hrow + 32);
        f32x4 acc[5];
        #pragma unroll
        for (int t = 0; t < 5; ++t) acc[t] = (f32x4){0.f, 0.f, 0.f, 0.f};
        #pragma unroll
        for (int ks = 0; ks < 2; ++ks) {
            #pragma unroll
            for (int t = 0; t < 5; ++t)
                acc[t] = __builtin_amdgcn_mfma_f32_16x16x32_bf16(
                    afrag[ks], bfrag[t][ks], acc[t], 0, 0, 0);
        }
        #pragma unroll
        for (int t = 0; t < 5; ++t) {
            const int g = t * 16 + m;
            #pragma unroll
            for (int r = 0; r < 4; ++r) {
                const size_t row = (size_t)(node0 + q * 4 + r);
                float v = acc[t][r] + biasv[t];
                if (g < N_CLS) y2[row * N_CLS + g] = __float2bfloat16(v);
                else           r2[row * N_CLS + (g - N_CLS)] = __float2bfloat16(v);
            }
        }
    }
}

// ---------------------------------------------------------------------------
// K4: per-block LDS-ELL build + gather + log_softmax (layer 2).  Same ELL
// rebuild as K2 (cheap: ~1.5K int LDS atomics/block), then the R0 gather2
// body with indices/degrees from LDS.
// ---------------------------------------------------------------------------
__global__ __launch_bounds__(512) void bucket_gather2(
    const __hip_bfloat16* __restrict__ y2,   // [N+1][40], row N zeroed
    const __hip_bfloat16* __restrict__ r2,   // [N][40]
    const uint* __restrict__ staged, const int* __restrict__ bucketCnt,
    float* __restrict__ out)
{
    __shared__ int lcnt[GNODES];
    __shared__ int lslots[GNODES * ELL_W + 64];
    const int pb = blockIdx.x >> 1;
    const int hf = blockIdx.x & 1;
    const int node0 = pb * BUCK_NODES + hf * GNODES;

    for (int i = threadIdx.x; i < GNODES; i += 512) lcnt[i] = 0;
    __syncthreads();

    int total = bucketCnt[pb]; if (total > BUCK_CAP) total = BUCK_CAP;
    const uint* sp = staged + (size_t)pb * BUCK_CAP;
    const int rel0 = hf * GNODES;
    for (int i = threadIdx.x; i < total; i += 512) {
        uint v = sp[i];
        int rel = (int)(v >> 17) - rel0;
        if (0 <= rel && rel < GNODES) {
            int pos = atomicAdd(&lcnt[rel], 1);
            if (pos < ELL_W) lslots[rel * ELL_W + pos] = (int)(v & 0x1FFFFu);
        }
    }
    __syncthreads();

    const int lane  = threadIdx.x & 63;
    const int wv    = threadIdx.x >> 6;
    const int lpair = lane & 31;
    const int p2    = (lane >> 5) * 4;
    const uint pre2 = (uint)(lpair < 20 ? lpair : 19) * 4u;
    const char* y2c = (const char*)y2;

    for (int n = wv; n < GNODES; n += 8) {
        const int node = node0 + n;
        const int degr = lcnt[n];
        const int idxv = lslots[n * ELL_W + lane];
        const int degc = degr < ELL_W ? degr : ELL_W;
        int idx = (lane >= degc) ? N_NODES : idxv;

        float a0 = 0.f, a1 = 0.f;
        const int groups = (degc + 7) & ~7;
        for (int e = 0; e < groups; e += 8) {
            int sel0 = __builtin_amdgcn_ds_bpermute(e * 4      + p2, idx);
            int sel1 = __builtin_amdgcn_ds_bpermute(e * 4 +  8 + p2, idx);
            int sel2 = __builtin_amdgcn_ds_bpermute(e * 4 + 16 + p2, idx);
            int sel3 = __builtin_amdgcn_ds_bpermute(e * 4 + 24 + p2, idx);
            uint d0 = *(const uint*)(y2c + ((size_t)(uint)sel0 * 80u + pre2));
            uint d1 = *(const uint*)(y2c + ((size_t)(uint)sel1 * 80u + pre2));
            uint d2 = *(const uint*)(y2c + ((size_t)(uint)sel2 * 80u + pre2));
            uint d3 = *(const uint*)(y2c + ((size_t)(uint)sel3 * 80u + pre2));
            a0 += __uint_as_float(d0 << 16) + __uint_as_float(d1 << 16)
                + __uint_as_float(d2 << 16) + __uint_as_float(d3 << 16);
            a1 += __uint_as_float(d0 & 0xffff0000u) + __uint_as_float(d1 & 0xffff0000u)
                + __uint_as_float(d2 & 0xffff0000u) + __uint_as_float(d3 & 0xffff0000u);
        }
        a0 += __shfl_xor(a0, 32);
        a1 += __shfl_xor(a1, 32);

        uint rr = *(const uint*)((const char*)r2 + ((size_t)node * 80u + pre2));
        float r0 = __uint_as_float(rr << 16);
        float r1 = __uint_as_float(rr & 0xffff0000u);

        float inv = 1.0f / (float)(degr > 1 ? degr : 1);
        float l0 = a0 * inv + r0;
        float l1 = a1 * inv + r1;
        if (lpair >= 20) { l0 = -INFINITY; l1 = -INFINITY; }

        float m = fmaxf(l0, l1);
        #pragma unroll
        for (int off = 16; off > 0; off >>= 1)
            m = fmaxf(m, __shfl_xor(m, off));
        float ex = (lpair < 20) ? (expf(l0 - m) + expf(l1 - m)) : 0.0f;
        #pragma unroll
        for (int off = 16; off > 0; off >>= 1)
            ex += __shfl_xor(ex, off);
        float lg = m + logf(ex);
        if (lane < 20) {
            float2 o = make_float2(l0 - lg, l1 - lg);
            *(float2*)(out + (size_t)node * N_CLS + lpair * 2) = o;
        }
    }
}

extern "C" void kernel_launch(void* const* d_in, const int* in_sizes, int n_in,
                              void* d_out, int out_size, void* d_ws, size_t ws_size,
                              hipStream_t stream)
{
    (void)in_sizes; (void)n_in; (void)out_size; (void)ws_size;

    const float* x    = (const float*)d_in[0];
    const int*   ei   = (const int*)d_in[1];      // [2, E]: src row, then dst row
    const float* W1_l = (const float*)d_in[2];
    const float* b1   = (const float*)d_in[3];
    const float* W1_r = (const float*)d_in[4];
    const float* W2_l = (const float*)d_in[5];
    const float* b2   = (const float*)d_in[6];
    const float* W2_r = (const float*)d_in[7];
    float* out = (float*)d_out;

    const int* src = ei;
    const int* dst = ei + N_EDGES;

    // workspace layout (bytes, ~44 MiB):
    //   bucketCnt : [0, 2000)
    //   staged    : [1M, +5.888MB)           u32[NBUCK*BUCK_CAP]
    //   y1/y2     : [8M, +12.81MB)           bf16[(N+1)*64]; y2 [(N+1)*40] overlays
    //   h (=r1)   : [21M, +12.8MB)           bf16[N*64]
    //   r2        : [34M, +8MB)              bf16[N*40]
    char* ws = (char*)d_ws;
    int*            bucketCnt = (int*)(ws);
    uint*           staged    = (uint*)(ws + (1u << 20));
    __hip_bfloat16* y1        = (__hip_bfloat16*)(ws + 8388608u);
    __hip_bfloat16* y2        = (__hip_bfloat16*)(ws + 8388608u);
    __hip_bfloat16* h         = (__hip_bfloat16*)(ws + 22020096u);  // also r1
    __hip_bfloat16* r2        = (__hip_bfloat16*)(ws + 35651584u);

    const int ntiles = N_NODES / 16;   // 6250, exact

    // K0: zero bucket counters; K1: edge bucketing || gemm1 (independent)
    hipMemsetAsync(bucketCnt, 0, NBUCK * sizeof(int), stream);
    stage_and_gemm1<<<NBLK_STAGE + NBLK_GEMM1, 256, 0, stream>>>(
        src, dst, bucketCnt, staged, x, W1_l, W1_r, b1, y1, h, ntiles);

    // K2: LDS-ELL build + gather + relu (h in place over r1)
    bucket_gather1<<<NBUCK * 2, 512, 0, stream>>>(y1, staged, bucketCnt, h);

    // K3: gemm2 (y2 overlays y1)
    gemm2_mfma<<<1024, 256, 0, stream>>>(h, W2_l, W2_r, b2, y2, r2, ntiles);

    // K4: LDS-ELL build + gather + log_softmax
    bucket_gather2<<<NBUCK * 2, 512, 0, stream>>>(y2, r2, staged, bucketCnt, out);
}